// Round 17
// baseline (773.293 us; speedup 1.0000x reference)
//
#include <hip/hip_runtime.h>
#include <hip/hip_bf16.h>
#include <hip/hip_fp8.h>

static constexpr int NINP = 128;
static constexpr int D2   = 256;

using u8  = unsigned char;
using u16 = unsigned short;
using u32 = unsigned int;

typedef __attribute__((ext_vector_type(8))) __bf16 bf16x8;
typedef __attribute__((ext_vector_type(4))) float f32x4;
typedef __attribute__((ext_vector_type(2))) float f32x2;

__device__ __forceinline__ float bf2f(u16 b) {
    union { u32 u; float f; } v;
    v.u = ((u32)b) << 16;
    return v.f;
}
__device__ __forceinline__ u16 f2bf(float f) {
    union { float f; u32 u; } v;
    v.f = f;
    u32 u = v.u + 0x7fff + ((v.u >> 16) & 1);  // RNE
    return (u16)(u >> 16);
}
__device__ __forceinline__ u32 pack2(float a, float b) {
    return (u32)f2bf(a) | ((u32)f2bf(b) << 16);
}
__device__ __forceinline__ float fp8tof(u8 b) {
    __hip_fp8_e4m3 v;
    v.__x = (__hip_fp8_storage_t)b;
    return (float)v;
}
__device__ __forceinline__ u8 ftofp8(float f) {
    __hip_fp8_e4m3 v(f);
    return (u8)v.__x;
}
// packed decode of 4 fp8-e4m3 in a dword (HW cvt_pk on gfx950)
__device__ __forceinline__ f32x4 fp8x4tof(u32 p) {
#if __has_builtin(__builtin_amdgcn_cvt_pk_f32_fp8)
    f32x2 lo = __builtin_amdgcn_cvt_pk_f32_fp8((int)p, false);
    f32x2 hi = __builtin_amdgcn_cvt_pk_f32_fp8((int)p, true);
    f32x4 r;
    r[0] = lo[0]; r[1] = lo[1]; r[2] = hi[0]; r[3] = hi[1];
    return r;
#else
    f32x4 r;
    r[0] = fp8tof((u8)(p & 0xff));
    r[1] = fp8tof((u8)((p >> 8) & 0xff));
    r[2] = fp8tof((u8)((p >> 16) & 0xff));
    r[3] = fp8tof((u8)(p >> 24));
    return r;
#endif
}

// bijective XCD chunk swizzle (m204): consecutive sids land on the same XCD
__device__ __forceinline__ int xcd_swz(int bid, int nb) {
    int q = nb >> 3, r = nb & 7;
    int x = bid & 7, j = bid >> 3;
    return (x < r ? x * (q + 1) : r * (q + 1) + (x - r) * q) + j;
}

// ---------------- graph build ----------------

__global__ void init_deg_kernel(int* __restrict__ deg, int n) {
    int i = blockIdx.x * blockDim.x + threadIdx.x;
    if (i < n) deg[i] = 0;
}

// 4 edges/thread: independent atomics issued back-to-back (MLP for latency hiding)
__global__ void count_kernel(const int* __restrict__ dst, int* __restrict__ deg, int E) {
    int base = (blockIdx.x * blockDim.x + threadIdx.x) * 4;
    int d[4];
#pragma unroll
    for (int j = 0; j < 4; ++j)
        if (base + j < E) d[j] = dst[base + j];
#pragma unroll
    for (int j = 0; j < 4; ++j)
        if (base + j < E) atomicAdd(&deg[d[j]], 1);
}

__global__ void dinv_kernel(const int* __restrict__ deg, float* __restrict__ dinv, int n) {
    int i = blockIdx.x * blockDim.x + threadIdx.x;
    if (i < n) dinv[i] = rsqrtf((float)deg[i] + 1.0f);
}

// zero the padded CSR arrays (pad slots: src=0, w=0 -> contribute exactly 0)
__global__ void init_csr_kernel(int* __restrict__ csr_src, float* __restrict__ csr_w, int cap) {
    int i = blockIdx.x * 256 + threadIdx.x;
    if (i < cap) {
        csr_src[i] = 0;
        csr_w[i] = 0.f;
    }
}

// 3-phase parallel scan over PADDED degrees (pad to multiple of 8)
__global__ __launch_bounds__(256) void scan_blk_kernel(const int* __restrict__ deg,
                                                       int* __restrict__ excl,
                                                       int* __restrict__ bsum, int n) {
    __shared__ int lds[256];
    int t = threadIdx.x;
    int i = blockIdx.x * 256 + t;
    int v = (i < n) ? ((deg[i] + 7) & ~7) : 0;
    lds[t] = v;
    __syncthreads();
    for (int off = 1; off < 256; off <<= 1) {
        int x = (t >= off) ? lds[t - off] : 0;
        __syncthreads();
        lds[t] += x;
        __syncthreads();
    }
    if (i < n) excl[i] = lds[t] - v;
    if (t == 255) bsum[blockIdx.x] = lds[255];
}

__global__ __launch_bounds__(1024) void scan_top_kernel(int* __restrict__ bsum, int nb) {
    __shared__ int lds[1024];
    int t = threadIdx.x;
    int v = (t < nb) ? bsum[t] : 0;
    lds[t] = v;
    __syncthreads();
    for (int off = 1; off < 1024; off <<= 1) {
        int x = (t >= off) ? lds[t - off] : 0;
        __syncthreads();
        lds[t] += x;
        __syncthreads();
    }
    if (t < nb) bsum[t] = lds[t] - v;
}

__global__ __launch_bounds__(256) void scan_add_kernel(const int* __restrict__ excl,
                                                       const int* __restrict__ bsum,
                                                       const int* __restrict__ deg,
                                                       int* __restrict__ row_start,
                                                       int* __restrict__ cursor, int n) {
    int i = blockIdx.x * 256 + threadIdx.x;
    if (i < n) {
        int r = excl[i] + bsum[blockIdx.x];
        row_start[i] = r;
        cursor[i] = r;
        if (i == n - 1) row_start[n] = r + ((deg[i] + 7) & ~7);
    }
}

// 4 edges/thread: independent atomic+scatter chains for MLP
__global__ void fill_csr_kernel(const int* __restrict__ src, const int* __restrict__ dst,
                                const float* __restrict__ dinv, int* __restrict__ cursor,
                                int* __restrict__ csr_src, float* __restrict__ csr_w, int E) {
    int base = (blockIdx.x * blockDim.x + threadIdx.x) * 4;
    int s[4], d[4], pos[4];
#pragma unroll
    for (int j = 0; j < 4; ++j)
        if (base + j < E) {
            s[j] = src[base + j];
            d[j] = dst[base + j];
        }
#pragma unroll
    for (int j = 0; j < 4; ++j)
        if (base + j < E) pos[j] = atomicAdd(&cursor[d[j]], 1);
#pragma unroll
    for (int j = 0; j < 4; ++j)
        if (base + j < E) {
            csr_src[pos[j]] = s[j];
            csr_w[pos[j]] = dinv[s[j]] * dinv[d[j]];
        }
}

// ---------------- weight transpose+convert: Wt[n][k] = bf16(W[k][n]) ----------------

__global__ void wt_kernel(const float* __restrict__ W, u16* __restrict__ Wt, int K, int N) {
    int i = blockIdx.x * 256 + threadIdx.x;
    if (i >= K * N) return;
    int n = i / K, k = i - n * K;
    Wt[i] = f2bf(W[(size_t)k * N + n]);
}

// ---------------- fp32 -> bf16 convert (vector) ----------------

__global__ void cvt_kernel(const float4* __restrict__ X, uint2* __restrict__ Xb, int n4) {
    int i = blockIdx.x * 256 + threadIdx.x;
    if (i >= n4) return;
    float4 v = X[i];
    uint2 p;
    p.x = pack2(v.x, v.y);
    p.y = pack2(v.z, v.w);
    Xb[i] = p;
}

// ---------------- bias + l2norm: X0b = bf16(l2norm(Hb + bias)) ----------------

__global__ __launch_bounds__(256) void l2n_kernel(const u16* __restrict__ Hb,
                                                  const float* __restrict__ bias,
                                                  u16* __restrict__ outb, int n) {
    int lane = threadIdx.x & 63;
    int node = blockIdx.x * 4 + (threadIdx.x >> 6);
    if (node >= n) return;
    int lv = lane * 4;
    size_t base = (size_t)node * D2 + lv;
    uint2 p = *(const uint2*)(Hb + base);
    float a0 = bf2f((u16)(p.x & 0xffff)) + bias[lv];
    float a1 = bf2f((u16)(p.x >> 16)) + bias[lv + 1];
    float a2 = bf2f((u16)(p.y & 0xffff)) + bias[lv + 2];
    float a3 = bf2f((u16)(p.y >> 16)) + bias[lv + 3];
    float ss = a0 * a0 + a1 * a1 + a2 * a2 + a3 * a3;
#pragma unroll
    for (int off = 32; off; off >>= 1) ss += __shfl_xor(ss, off);
    float scale = 1.0f / fmaxf(sqrtf(ss), 1e-12f);
    uint2 q;
    q.x = pack2(a0 * scale, a1 * scale);
    q.y = pack2(a2 * scale, a3 * scale);
    *(uint2*)(outb + base) = q;
}

// ---------------- MFMA GEMM (R8 design + XCD swizzle) ----------------
// C[M,N] = A[M,K] bf16 @ Bt[N,K] bf16; C stored bf16 (FP8OUT=0) or fp8-e4m3 (FP8OUT=1).
// BM=128, BN=128, BK=32; 4 waves (2x2), per-wave 64x64 = 4x4 frags of 16x16.

template <int FP8OUT>
__global__ __launch_bounds__(256, 2) void gemm_bf16(const u16* __restrict__ A,
                                                    const u16* __restrict__ Bt,
                                                    void* __restrict__ Cv,
                                                    int M, int K, int N, int nbn) {
    constexpr int BM = 128, BK = 32;
    constexpr int AST = BK + 8;
    __shared__ u16 As[BM * AST];

    int sid = xcd_swz(blockIdx.x, gridDim.x);
    int bm = (sid / nbn) * BM;
    int bn = (sid % nbn) * 128;

    int tid = threadIdx.x;
    int lane = tid & 63, wid = tid >> 6;
    int wr = wid >> 1, wc = wid & 1;
    int l15 = lane & 15, l4 = lane >> 4;

    f32x4 acc[4][4] = {};

    int sr = tid >> 1;
    int sh = (tid & 1) * 16;
    int arow = bm + sr;
    const u16* ap = A + (size_t)arow * K + sh;
    bool aval = arow < M;

    uint4 a0 = make_uint4(0, 0, 0, 0), a1 = a0;
    if (aval) {
        const uint4* p = (const uint4*)ap;
        a0 = p[0];
        a1 = p[1];
    }

    for (int k0 = 0; k0 < K; k0 += BK) {
        __syncthreads();
        *(uint4*)(&As[sr * AST + sh]) = a0;
        *(uint4*)(&As[sr * AST + sh + 8]) = a1;
        __syncthreads();

        if (k0 + BK < K && aval) {
            const uint4* p = (const uint4*)(ap + k0 + BK);
            a0 = p[0];
            a1 = p[1];
        }

        bf16x8 bfrag[4];
#pragma unroll
        for (int nf = 0; nf < 4; ++nf) {
            int col = bn + wc * 64 + nf * 16 + l15;
            bfrag[nf] = *(const bf16x8*)(Bt + (size_t)col * K + k0 + l4 * 8);
        }
        bf16x8 afrag[4];
#pragma unroll
        for (int mf = 0; mf < 4; ++mf) {
            int row = wr * 64 + mf * 16 + l15;
            afrag[mf] = *(const bf16x8*)(&As[row * AST + l4 * 8]);
        }
#pragma unroll
        for (int mf = 0; mf < 4; ++mf)
#pragma unroll
            for (int nf = 0; nf < 4; ++nf)
                acc[mf][nf] = __builtin_amdgcn_mfma_f32_16x16x32_bf16(afrag[mf], bfrag[nf],
                                                                      acc[mf][nf], 0, 0, 0);
    }

#pragma unroll
    for (int mf = 0; mf < 4; ++mf) {
#pragma unroll
        for (int nf = 0; nf < 4; ++nf) {
            int col = bn + wc * 64 + nf * 16 + l15;
#pragma unroll
            for (int r = 0; r < 4; ++r) {
                int row = bm + wr * 64 + mf * 16 + l4 * 4 + r;
                if (row < M) {
                    if constexpr (FP8OUT) {
                        ((u8*)Cv)[(size_t)row * N + col] = ftofp8(acc[mf][nf][r]);
                    } else {
                        ((u16*)Cv)[(size_t)row * N + col] = f2bf(acc[mf][nf][r]);
                    }
                }
            }
        }
    }
}

// ---------------- aggregation (fp32 accumulate; rows padded to multiple of 8) ----------------
// agg[i] = sum_e w_e*H[src_e] + dinv2[i]*H[i] (+ bias, per EPI); pad edges have w=0.
// FP8: gather table is fp8-e4m3 (packed cvt_pk decode); else bf16.
// EPI 0 (VEC=2): out fp32 = agg + bias                  (final conv)
// EPI 4 (VEC=2): outb bf16 = agg, NO bias               (S·emb for conv1)
// EPI 1 (VEC=4): outb bf16 = l2norm(agg + bias)
// EPI 3 (VEC=4): fused RK4, all-bf16 state

template <int VEC, int EPI, int FP8>
__global__ __launch_bounds__(256) void agg_kernel(const void* __restrict__ Hv,
                                                  const float* __restrict__ bias,
                                                  const u16* __restrict__ Zb,
                                                  const u16* __restrict__ X0bb,
                                                  u16* __restrict__ ACCb,
                                                  const int* __restrict__ row_start,
                                                  const int* __restrict__ csr_src,
                                                  const float* __restrict__ csr_w,
                                                  const float* __restrict__ dinv,
                                                  float* __restrict__ out,
                                                  u16* __restrict__ outb,
                                                  float ca, float cx, int accInit, int writeXT,
                                                  int n) {
    const int F = VEC * 64;
    int lane = threadIdx.x & 63;
    int node = blockIdx.x * 4 + (threadIdx.x >> 6);
    if (node >= n) return;

    const u16* Hb = (const u16*)Hv;
    const u8*  H8 = (const u8*)Hv;

    float acc[VEC];
    float di = dinv[node];
    float d2 = di * di;
    int lv = lane * VEC;
    size_t base = (size_t)node * F + lv;

    if constexpr (FP8) {  // VEC == 4
        f32x4 h = fp8x4tof(*(const u32*)(H8 + base));
#pragma unroll
        for (int v = 0; v < 4; ++v) acc[v] = d2 * h[v];
    } else if constexpr (VEC == 4) {
        uint2 p = *(const uint2*)(Hb + base);
        acc[0] = d2 * bf2f((u16)(p.x & 0xffff));
        acc[1] = d2 * bf2f((u16)(p.x >> 16));
        acc[2] = d2 * bf2f((u16)(p.y & 0xffff));
        acc[3] = d2 * bf2f((u16)(p.y >> 16));
    } else {
        u32 p = *(const u32*)(Hb + base);
        acc[0] = d2 * bf2f((u16)(p & 0xffff));
        acc[1] = d2 * bf2f((u16)(p >> 16));
    }

    int e = row_start[node], end = row_start[node + 1];  // end-e is a multiple of 8
    if constexpr (FP8) {
        for (; e < end; e += 8) {
            u32 pp[8];
            float ww[8];
#pragma unroll
            for (int j = 0; j < 8; ++j) {
                int s = csr_src[e + j];
                ww[j] = csr_w[e + j];
                pp[j] = *(const u32*)(H8 + (size_t)s * F + lv);
            }
#pragma unroll
            for (int j = 0; j < 8; ++j) {
                f32x4 h = fp8x4tof(pp[j]);
#pragma unroll
                for (int v = 0; v < 4; ++v) acc[v] += ww[j] * h[v];
            }
        }
    } else if constexpr (VEC == 4) {
        for (; e < end; e += 8) {
            uint2 pp[8];
            float ww[8];
#pragma unroll
            for (int j = 0; j < 8; ++j) {
                int s = csr_src[e + j];
                ww[j] = csr_w[e + j];
                pp[j] = *(const uint2*)(Hb + (size_t)s * F + lv);
            }
#pragma unroll
            for (int j = 0; j < 8; ++j) {
                acc[0] += ww[j] * bf2f((u16)(pp[j].x & 0xffff));
                acc[1] += ww[j] * bf2f((u16)(pp[j].x >> 16));
                acc[2] += ww[j] * bf2f((u16)(pp[j].y & 0xffff));
                acc[3] += ww[j] * bf2f((u16)(pp[j].y >> 16));
            }
        }
    } else {
        for (; e < end; e += 4) {
            u32 pp[4];
            float ww[4];
#pragma unroll
            for (int j = 0; j < 4; ++j) {
                int s = csr_src[e + j];
                ww[j] = csr_w[e + j];
                pp[j] = *(const u32*)(Hb + (size_t)s * F + lv);
            }
#pragma unroll
            for (int j = 0; j < 4; ++j) {
                acc[0] += ww[j] * bf2f((u16)(pp[j] & 0xffff));
                acc[1] += ww[j] * bf2f((u16)(pp[j] >> 16));
            }
        }
    }

    if constexpr (EPI != 4) {
#pragma unroll
        for (int v = 0; v < VEC; ++v) acc[v] += bias[lv + v];
    }

    if constexpr (EPI == 0) {
        *(float2*)(out + base) = make_float2(acc[0], acc[1]);
    } else if constexpr (EPI == 4) {
        *(u32*)(outb + base) = pack2(acc[0], acc[1]);
    } else if constexpr (EPI == 1) {
        float ss = 0.f;
#pragma unroll
        for (int v = 0; v < VEC; ++v) ss += acc[v] * acc[v];
#pragma unroll
        for (int off = 32; off; off >>= 1) ss += __shfl_xor(ss, off);
        float scale = 1.0f / fmaxf(sqrtf(ss), 1e-12f);
        uint2 p;
        p.x = pack2(acc[0] * scale, acc[1] * scale);
        p.y = pack2(acc[2] * scale, acc[3] * scale);
        *(uint2*)(outb + base) = p;
    } else {  // EPI == 3, VEC == 4
        uint2 zp = *(const uint2*)(Zb + base);
        float k0 = acc[0] + bf2f((u16)(zp.x & 0xffff));
        float k1 = acc[1] + bf2f((u16)(zp.x >> 16));
        float k2 = acc[2] + bf2f((u16)(zp.y & 0xffff));
        float k3 = acc[3] + bf2f((u16)(zp.y >> 16));
        uint2 ap = accInit ? *(const uint2*)(X0bb + base)
                           : *(const uint2*)(ACCb + base);
        float a0 = bf2f((u16)(ap.x & 0xffff)) + ca * k0;
        float a1 = bf2f((u16)(ap.x >> 16))    + ca * k1;
        float a2 = bf2f((u16)(ap.y & 0xffff)) + ca * k2;
        float a3 = bf2f((u16)(ap.y >> 16))    + ca * k3;
        uint2 av;
        av.x = pack2(a0, a1);
        av.y = pack2(a2, a3);
        *(uint2*)(ACCb + base) = av;
        if (writeXT) {
            uint2 xp = *(const uint2*)(X0bb + base);
            float x0 = bf2f((u16)(xp.x & 0xffff));
            float x1 = bf2f((u16)(xp.x >> 16));
            float x2 = bf2f((u16)(xp.y & 0xffff));
            float x3 = bf2f((u16)(xp.y >> 16));
            uint2 p;
            p.x = pack2(x0 + cx * k0, x1 + cx * k1);
            p.y = pack2(x2 + cx * k2, x3 + cx * k3);
            *(uint2*)(outb + base) = p;
        }
    }
}

// ---------------- launch ----------------

extern "C" void kernel_launch(void* const* d_in, const int* in_sizes, int n_in,
                              void* d_out, int out_size, void* d_ws, size_t ws_size,
                              hipStream_t stream) {
    const float* emb = (const float*)d_in[0];
    const int* ei    = (const int*)d_in[1];
    const float* W1  = (const float*)d_in[2];
    const float* b1  = (const float*)d_in[3];
    const float* Wf1 = (const float*)d_in[4];
    const float* bf1 = (const float*)d_in[5];
    const float* Wf2 = (const float*)d_in[6];
    const float* bf2 = (const float*)d_in[7];
    const float* W2  = (const float*)d_in[8];
    const float* b2  = (const float*)d_in[9];
    float* out = (float*)d_out;

    const int N = in_sizes[0] / NINP;  // 50000
    const int E = in_sizes[1] / 2;     // 800000
    const int* esrc = ei;
    const int* edst = ei + E;
    const int Ecap = E + 8 * N;        // padded CSR capacity

    char* p = (char*)d_ws;
    auto alloc = [&](size_t bytes) -> char* {
        char* r = p;
        p += (bytes + 255) & ~(size_t)255;
        return r;
    };
    int*   deg       = (int*)alloc((size_t)N * 4);
    float* dinv      = (float*)alloc((size_t)N * 4);
    int*   row_start = (int*)alloc((size_t)(N + 1) * 4);
    int*   cursor    = (int*)alloc((size_t)N * 4);
    int*   sc_excl   = (int*)alloc((size_t)N * 4);
    int*   sc_bsum   = (int*)alloc((size_t)1024 * 4);
    int*   csr_src   = (int*)alloc((size_t)Ecap * 4);
    float* csr_w     = (float*)alloc((size_t)Ecap * 4);
    u16*   Hb    = (u16*)alloc((size_t)N * D2 * 2);
    u8*    Hq    = (u8*)alloc((size_t)N * D2);       // fp8 gather table (EPI1 + EPI3 inputs)
    u16*   ACCb  = (u16*)alloc((size_t)N * D2 * 2);  // RK4 accumulator (bf16)
    u16*   X0b   = (u16*)alloc((size_t)N * D2 * 2);
    u16*   XTb   = (u16*)alloc((size_t)N * D2 * 2);  // aliased by embb (disjoint lifetime)
    u16*   Z1b   = (u16*)alloc((size_t)N * D2 * 2);
    u16*   Eb    = (u16*)alloc((size_t)N * NINP * 2); // S·emb (bf16)
    u16*   W1t   = (u16*)alloc((size_t)NINP * D2 * 2);
    u16*   Wf1t  = (u16*)alloc((size_t)D2 * D2 * 2);
    u16*   Wf2t  = (u16*)alloc((size_t)D2 * D2 * 2);
    u16*   W2t   = (u16*)alloc((size_t)D2 * NINP * 2);
    u16*   embb  = XTb;

    const int gN = (N + 255) / 256, gE = (E + 255) / 256;
    const int gE4 = (E + 1023) / 1024;
    init_deg_kernel<<<gN, 256, 0, stream>>>(deg, N);
    count_kernel<<<gE4, 256, 0, stream>>>(edst, deg, E);
    dinv_kernel<<<gN, 256, 0, stream>>>(deg, dinv, N);
    init_csr_kernel<<<(Ecap + 255) / 256, 256, 0, stream>>>(csr_src, csr_w, Ecap);
    scan_blk_kernel<<<gN, 256, 0, stream>>>(deg, sc_excl, sc_bsum, N);
    scan_top_kernel<<<1, 1024, 0, stream>>>(sc_bsum, gN);
    scan_add_kernel<<<gN, 256, 0, stream>>>(sc_excl, sc_bsum, deg, row_start, cursor, N);
    fill_csr_kernel<<<gE4, 256, 0, stream>>>(esrc, edst, dinv, cursor, csr_src, csr_w, E);

    wt_kernel<<<(NINP * D2 + 255) / 256, 256, 0, stream>>>(W1, W1t, NINP, D2);
    wt_kernel<<<(D2 * D2 + 255) / 256, 256, 0, stream>>>(Wf1, Wf1t, D2, D2);
    wt_kernel<<<(D2 * D2 + 255) / 256, 256, 0, stream>>>(Wf2, Wf2t, D2, D2);
    wt_kernel<<<(D2 * NINP + 255) / 256, 256, 0, stream>>>(W2, W2t, D2, NINP);
    cvt_kernel<<<(N * NINP / 4 + 255) / 256, 256, 0, stream>>>((const float4*)emb, (uint2*)embb,
                                                               N * NINP / 4);

    auto gemmB = [&](const u16* A, const u16* Bt, u16* C, int K, int Ncols) {
        int nbm = (N + 127) / 128, nbn = Ncols / 128;
        gemm_bf16<0><<<nbm * nbn, 256, 0, stream>>>(A, Bt, (void*)C, N, K, Ncols, nbn);
    };
    auto gemmQ = [&](const u16* A, const u16* Bt, u8* C, int K, int Ncols) {
        int nbm = (N + 127) / 128, nbn = Ncols / 128;
        gemm_bf16<1><<<nbm * nbn, 256, 0, stream>>>(A, Bt, (void*)C, N, K, Ncols, nbn);
    };
    const int gAgg = (N + 3) / 4;

    // conv1 swapped: Eb = S·emb (128-dim gather), gemm, then bias+l2norm -> X0b
    agg_kernel<2, 4, 0><<<gAgg, 256, 0, stream>>>(embb, nullptr, nullptr, nullptr, nullptr,
                                                  row_start, csr_src, csr_w, dinv, nullptr, Eb,
                                                  0.f, 0.f, 0, 0, N);
    gemmB(Eb, W1t, Hb, NINP, D2);
    l2n_kernel<<<gAgg, 256, 0, stream>>>(Hb, b1, X0b, N);

    // f(z) + fused RK4 stage: BOTH inner gathers on fp8 tables (Hq reused sequentially)
    auto fstage = [&](const u16* zb, const u16* zres, float ca, float cx, int accInit,
                      int writeXT, u16* outb) {
        gemmQ(zb, Wf1t, Hq, D2, D2);
        agg_kernel<4, 1, 1><<<gAgg, 256, 0, stream>>>(Hq, bf1, nullptr, nullptr, nullptr,
                                                      row_start, csr_src, csr_w, dinv, nullptr,
                                                      Z1b, 0.f, 0.f, 0, 0, N);
        gemmQ(Z1b, Wf2t, Hq, D2, D2);
        agg_kernel<4, 3, 1><<<gAgg, 256, 0, stream>>>(Hq, bf2, zres, X0b, ACCb,
                                                      row_start, csr_src, csr_w, dinv, nullptr,
                                                      outb, ca, cx, accInit, writeXT, N);
    };

    fstage(X0b, X0b, 1.f / 6.f, 0.5f, 1, 1, XTb);     // k1
    fstage(XTb, XTb, 1.f / 3.f, 0.5f, 0, 1, XTb);     // k2
    fstage(XTb, XTb, 1.f / 3.f, 1.0f, 0, 1, XTb);     // k3
    fstage(XTb, XTb, 1.f / 6.f, 0.0f, 0, 0, nullptr); // k4 -> ACCb (bf16)

    // final conv -> d_out (fp32)
    gemmB(ACCb, W2t, Hb, D2, NINP);
    agg_kernel<2, 0, 0><<<gAgg, 256, 0, stream>>>(Hb, b2, nullptr, nullptr, nullptr,
                                                  row_start, csr_src, csr_w, dinv, out, nullptr,
                                                  0.f, 0.f, 0, 0, N);
}

// Round 18
// 765.671 us; speedup vs baseline: 1.0100x; 1.0100x over previous
//
#include <hip/hip_runtime.h>
#include <hip/hip_bf16.h>
#include <hip/hip_fp8.h>

static constexpr int NINP = 128;
static constexpr int D2   = 256;

using u8  = unsigned char;
using u16 = unsigned short;
using u32 = unsigned int;

typedef __attribute__((ext_vector_type(8))) __bf16 bf16x8;
typedef __attribute__((ext_vector_type(4))) float f32x4;
typedef __attribute__((ext_vector_type(2))) float f32x2;

__device__ __forceinline__ float bf2f(u16 b) {
    union { u32 u; float f; } v;
    v.u = ((u32)b) << 16;
    return v.f;
}
__device__ __forceinline__ u16 f2bf(float f) {
    union { float f; u32 u; } v;
    v.f = f;
    u32 u = v.u + 0x7fff + ((v.u >> 16) & 1);  // RNE
    return (u16)(u >> 16);
}
__device__ __forceinline__ u32 pack2(float a, float b) {
    return (u32)f2bf(a) | ((u32)f2bf(b) << 16);
}
__device__ __forceinline__ float fp8tof(u8 b) {
    __hip_fp8_e4m3 v;
    v.__x = (__hip_fp8_storage_t)b;
    return (float)v;
}
__device__ __forceinline__ u8 ftofp8(float f) {
    __hip_fp8_e4m3 v(f);
    return (u8)v.__x;
}
// packed decode of 4 fp8-e4m3 in a dword (HW cvt_pk on gfx950)
__device__ __forceinline__ f32x4 fp8x4tof(u32 p) {
#if __has_builtin(__builtin_amdgcn_cvt_pk_f32_fp8)
    f32x2 lo = __builtin_amdgcn_cvt_pk_f32_fp8((int)p, false);
    f32x2 hi = __builtin_amdgcn_cvt_pk_f32_fp8((int)p, true);
    f32x4 r;
    r[0] = lo[0]; r[1] = lo[1]; r[2] = hi[0]; r[3] = hi[1];
    return r;
#else
    f32x4 r;
    r[0] = fp8tof((u8)(p & 0xff));
    r[1] = fp8tof((u8)((p >> 8) & 0xff));
    r[2] = fp8tof((u8)((p >> 16) & 0xff));
    r[3] = fp8tof((u8)(p >> 24));
    return r;
#endif
}

// bijective XCD chunk swizzle (m204): consecutive sids land on the same XCD
__device__ __forceinline__ int xcd_swz(int bid, int nb) {
    int q = nb >> 3, r = nb & 7;
    int x = bid & 7, j = bid >> 3;
    return (x < r ? x * (q + 1) : r * (q + 1) + (x - r) * q) + j;
}

// ---------------- graph build ----------------

__global__ void init_deg_kernel(int* __restrict__ deg, int n) {
    int i = blockIdx.x * blockDim.x + threadIdx.x;
    if (i < n) deg[i] = 0;
}

// 2 edges/thread: MLP depth 2 while keeping grid large (occupancy)
__global__ void count_kernel(const int* __restrict__ dst, int* __restrict__ deg, int E) {
    int base = (blockIdx.x * blockDim.x + threadIdx.x) * 2;
    int d[2];
#pragma unroll
    for (int j = 0; j < 2; ++j)
        if (base + j < E) d[j] = dst[base + j];
#pragma unroll
    for (int j = 0; j < 2; ++j)
        if (base + j < E) atomicAdd(&deg[d[j]], 1);
}

__global__ void dinv_kernel(const int* __restrict__ deg, float* __restrict__ dinv, int n) {
    int i = blockIdx.x * blockDim.x + threadIdx.x;
    if (i < n) dinv[i] = rsqrtf((float)deg[i] + 1.0f);
}

// zero the padded CSR arrays (pad slots: src=0, w=0 -> contribute exactly 0)
__global__ void init_csr_kernel(int* __restrict__ csr_src, float* __restrict__ csr_w, int cap) {
    int i = blockIdx.x * 256 + threadIdx.x;
    if (i < cap) {
        csr_src[i] = 0;
        csr_w[i] = 0.f;
    }
}

// 3-phase parallel scan over PADDED degrees (pad to multiple of 8)
__global__ __launch_bounds__(256) void scan_blk_kernel(const int* __restrict__ deg,
                                                       int* __restrict__ excl,
                                                       int* __restrict__ bsum, int n) {
    __shared__ int lds[256];
    int t = threadIdx.x;
    int i = blockIdx.x * 256 + t;
    int v = (i < n) ? ((deg[i] + 7) & ~7) : 0;
    lds[t] = v;
    __syncthreads();
    for (int off = 1; off < 256; off <<= 1) {
        int x = (t >= off) ? lds[t - off] : 0;
        __syncthreads();
        lds[t] += x;
        __syncthreads();
    }
    if (i < n) excl[i] = lds[t] - v;
    if (t == 255) bsum[blockIdx.x] = lds[255];
}

__global__ __launch_bounds__(1024) void scan_top_kernel(int* __restrict__ bsum, int nb) {
    __shared__ int lds[1024];
    int t = threadIdx.x;
    int v = (t < nb) ? bsum[t] : 0;
    lds[t] = v;
    __syncthreads();
    for (int off = 1; off < 1024; off <<= 1) {
        int x = (t >= off) ? lds[t - off] : 0;
        __syncthreads();
        lds[t] += x;
        __syncthreads();
    }
    if (t < nb) bsum[t] = lds[t] - v;
}

__global__ __launch_bounds__(256) void scan_add_kernel(const int* __restrict__ excl,
                                                       const int* __restrict__ bsum,
                                                       const int* __restrict__ deg,
                                                       int* __restrict__ row_start,
                                                       int* __restrict__ cursor, int n) {
    int i = blockIdx.x * 256 + threadIdx.x;
    if (i < n) {
        int r = excl[i] + bsum[blockIdx.x];
        row_start[i] = r;
        cursor[i] = r;
        if (i == n - 1) row_start[n] = r + ((deg[i] + 7) & ~7);
    }
}

// 2 edges/thread: MLP depth 2 with a large grid
__global__ void fill_csr_kernel(const int* __restrict__ src, const int* __restrict__ dst,
                                const float* __restrict__ dinv, int* __restrict__ cursor,
                                int* __restrict__ csr_src, float* __restrict__ csr_w, int E) {
    int base = (blockIdx.x * blockDim.x + threadIdx.x) * 2;
    int s[2], d[2], pos[2];
#pragma unroll
    for (int j = 0; j < 2; ++j)
        if (base + j < E) {
            s[j] = src[base + j];
            d[j] = dst[base + j];
        }
#pragma unroll
    for (int j = 0; j < 2; ++j)
        if (base + j < E) pos[j] = atomicAdd(&cursor[d[j]], 1);
#pragma unroll
    for (int j = 0; j < 2; ++j)
        if (base + j < E) {
            csr_src[pos[j]] = s[j];
            csr_w[pos[j]] = dinv[s[j]] * dinv[d[j]];
        }
}

// ---------------- weight transpose+convert: Wt[n][k] = bf16(W[k][n]) ----------------

__global__ void wt_kernel(const float* __restrict__ W, u16* __restrict__ Wt, int K, int N) {
    int i = blockIdx.x * 256 + threadIdx.x;
    if (i >= K * N) return;
    int n = i / K, k = i - n * K;
    Wt[i] = f2bf(W[(size_t)k * N + n]);
}

// ---------------- fp32 -> bf16 convert (vector) ----------------

__global__ void cvt_kernel(const float4* __restrict__ X, uint2* __restrict__ Xb, int n4) {
    int i = blockIdx.x * 256 + threadIdx.x;
    if (i >= n4) return;
    float4 v = X[i];
    uint2 p;
    p.x = pack2(v.x, v.y);
    p.y = pack2(v.z, v.w);
    Xb[i] = p;
}

// ---------------- bias + l2norm: X0b = bf16(l2norm(Hb + bias)) ----------------

__global__ __launch_bounds__(256) void l2n_kernel(const u16* __restrict__ Hb,
                                                  const float* __restrict__ bias,
                                                  u16* __restrict__ outb, int n) {
    int lane = threadIdx.x & 63;
    int node = blockIdx.x * 4 + (threadIdx.x >> 6);
    if (node >= n) return;
    int lv = lane * 4;
    size_t base = (size_t)node * D2 + lv;
    uint2 p = *(const uint2*)(Hb + base);
    float a0 = bf2f((u16)(p.x & 0xffff)) + bias[lv];
    float a1 = bf2f((u16)(p.x >> 16)) + bias[lv + 1];
    float a2 = bf2f((u16)(p.y & 0xffff)) + bias[lv + 2];
    float a3 = bf2f((u16)(p.y >> 16)) + bias[lv + 3];
    float ss = a0 * a0 + a1 * a1 + a2 * a2 + a3 * a3;
#pragma unroll
    for (int off = 32; off; off >>= 1) ss += __shfl_xor(ss, off);
    float scale = 1.0f / fmaxf(sqrtf(ss), 1e-12f);
    uint2 q;
    q.x = pack2(a0 * scale, a1 * scale);
    q.y = pack2(a2 * scale, a3 * scale);
    *(uint2*)(outb + base) = q;
}

// ---------------- MFMA GEMM (R8 design + XCD swizzle) ----------------
// C[M,N] = A[M,K] bf16 @ Bt[N,K] bf16; C stored bf16 (FP8OUT=0) or fp8-e4m3 (FP8OUT=1).
// BM=128, BN=128, BK=32; 4 waves (2x2), per-wave 64x64 = 4x4 frags of 16x16.

template <int FP8OUT>
__global__ __launch_bounds__(256, 2) void gemm_bf16(const u16* __restrict__ A,
                                                    const u16* __restrict__ Bt,
                                                    void* __restrict__ Cv,
                                                    int M, int K, int N, int nbn) {
    constexpr int BM = 128, BK = 32;
    constexpr int AST = BK + 8;
    __shared__ u16 As[BM * AST];

    int sid = xcd_swz(blockIdx.x, gridDim.x);
    int bm = (sid / nbn) * BM;
    int bn = (sid % nbn) * 128;

    int tid = threadIdx.x;
    int lane = tid & 63, wid = tid >> 6;
    int wr = wid >> 1, wc = wid & 1;
    int l15 = lane & 15, l4 = lane >> 4;

    f32x4 acc[4][4] = {};

    int sr = tid >> 1;
    int sh = (tid & 1) * 16;
    int arow = bm + sr;
    const u16* ap = A + (size_t)arow * K + sh;
    bool aval = arow < M;

    uint4 a0 = make_uint4(0, 0, 0, 0), a1 = a0;
    if (aval) {
        const uint4* p = (const uint4*)ap;
        a0 = p[0];
        a1 = p[1];
    }

    for (int k0 = 0; k0 < K; k0 += BK) {
        __syncthreads();
        *(uint4*)(&As[sr * AST + sh]) = a0;
        *(uint4*)(&As[sr * AST + sh + 8]) = a1;
        __syncthreads();

        if (k0 + BK < K && aval) {
            const uint4* p = (const uint4*)(ap + k0 + BK);
            a0 = p[0];
            a1 = p[1];
        }

        bf16x8 bfrag[4];
#pragma unroll
        for (int nf = 0; nf < 4; ++nf) {
            int col = bn + wc * 64 + nf * 16 + l15;
            bfrag[nf] = *(const bf16x8*)(Bt + (size_t)col * K + k0 + l4 * 8);
        }
        bf16x8 afrag[4];
#pragma unroll
        for (int mf = 0; mf < 4; ++mf) {
            int row = wr * 64 + mf * 16 + l15;
            afrag[mf] = *(const bf16x8*)(&As[row * AST + l4 * 8]);
        }
#pragma unroll
        for (int mf = 0; mf < 4; ++mf)
#pragma unroll
            for (int nf = 0; nf < 4; ++nf)
                acc[mf][nf] = __builtin_amdgcn_mfma_f32_16x16x32_bf16(afrag[mf], bfrag[nf],
                                                                      acc[mf][nf], 0, 0, 0);
    }

#pragma unroll
    for (int mf = 0; mf < 4; ++mf) {
#pragma unroll
        for (int nf = 0; nf < 4; ++nf) {
            int col = bn + wc * 64 + nf * 16 + l15;
#pragma unroll
            for (int r = 0; r < 4; ++r) {
                int row = bm + wr * 64 + mf * 16 + l4 * 4 + r;
                if (row < M) {
                    if constexpr (FP8OUT) {
                        ((u8*)Cv)[(size_t)row * N + col] = ftofp8(acc[mf][nf][r]);
                    } else {
                        ((u16*)Cv)[(size_t)row * N + col] = f2bf(acc[mf][nf][r]);
                    }
                }
            }
        }
    }
}

// ---------------- aggregation (fp32 accumulate; rows padded to multiple of 8) ----------------
// agg[i] = sum_e w_e*H[src_e] + dinv2[i]*H[i] (+ bias, per EPI); pad edges have w=0.
// FP8: gather table is fp8-e4m3 (packed cvt_pk decode); else bf16.
// EPI 0 (VEC=2): out fp32 = agg + bias                  (final conv)
// EPI 4 (VEC=2): outb bf16 = agg, NO bias               (S·emb for conv1)
// EPI 1 (VEC=4): outb bf16 = l2norm(agg + bias)
// EPI 3 (VEC=4): fused RK4, all-bf16 state

template <int VEC, int EPI, int FP8>
__global__ __launch_bounds__(256) void agg_kernel(const void* __restrict__ Hv,
                                                  const float* __restrict__ bias,
                                                  const u16* __restrict__ Zb,
                                                  const u16* __restrict__ X0bb,
                                                  u16* __restrict__ ACCb,
                                                  const int* __restrict__ row_start,
                                                  const int* __restrict__ csr_src,
                                                  const float* __restrict__ csr_w,
                                                  const float* __restrict__ dinv,
                                                  float* __restrict__ out,
                                                  u16* __restrict__ outb,
                                                  float ca, float cx, int accInit, int writeXT,
                                                  int n) {
    const int F = VEC * 64;
    int lane = threadIdx.x & 63;
    int node = blockIdx.x * 4 + (threadIdx.x >> 6);
    if (node >= n) return;

    const u16* Hb = (const u16*)Hv;
    const u8*  H8 = (const u8*)Hv;

    float acc[VEC];
    float di = dinv[node];
    float d2 = di * di;
    int lv = lane * VEC;
    size_t base = (size_t)node * F + lv;

    if constexpr (FP8) {  // VEC == 4
        f32x4 h = fp8x4tof(*(const u32*)(H8 + base));
#pragma unroll
        for (int v = 0; v < 4; ++v) acc[v] = d2 * h[v];
    } else if constexpr (VEC == 4) {
        uint2 p = *(const uint2*)(Hb + base);
        acc[0] = d2 * bf2f((u16)(p.x & 0xffff));
        acc[1] = d2 * bf2f((u16)(p.x >> 16));
        acc[2] = d2 * bf2f((u16)(p.y & 0xffff));
        acc[3] = d2 * bf2f((u16)(p.y >> 16));
    } else {
        u32 p = *(const u32*)(Hb + base);
        acc[0] = d2 * bf2f((u16)(p & 0xffff));
        acc[1] = d2 * bf2f((u16)(p >> 16));
    }

    int e = row_start[node], end = row_start[node + 1];  // end-e is a multiple of 8
    if constexpr (FP8) {
        for (; e < end; e += 8) {
            u32 pp[8];
            float ww[8];
#pragma unroll
            for (int j = 0; j < 8; ++j) {
                int s = csr_src[e + j];
                ww[j] = csr_w[e + j];
                pp[j] = *(const u32*)(H8 + (size_t)s * F + lv);
            }
#pragma unroll
            for (int j = 0; j < 8; ++j) {
                f32x4 h = fp8x4tof(pp[j]);
#pragma unroll
                for (int v = 0; v < 4; ++v) acc[v] += ww[j] * h[v];
            }
        }
    } else if constexpr (VEC == 4) {
        for (; e < end; e += 8) {
            uint2 pp[8];
            float ww[8];
#pragma unroll
            for (int j = 0; j < 8; ++j) {
                int s = csr_src[e + j];
                ww[j] = csr_w[e + j];
                pp[j] = *(const uint2*)(Hb + (size_t)s * F + lv);
            }
#pragma unroll
            for (int j = 0; j < 8; ++j) {
                acc[0] += ww[j] * bf2f((u16)(pp[j].x & 0xffff));
                acc[1] += ww[j] * bf2f((u16)(pp[j].x >> 16));
                acc[2] += ww[j] * bf2f((u16)(pp[j].y & 0xffff));
                acc[3] += ww[j] * bf2f((u16)(pp[j].y >> 16));
            }
        }
    } else {
        for (; e < end; e += 4) {
            u32 pp[4];
            float ww[4];
#pragma unroll
            for (int j = 0; j < 4; ++j) {
                int s = csr_src[e + j];
                ww[j] = csr_w[e + j];
                pp[j] = *(const u32*)(Hb + (size_t)s * F + lv);
            }
#pragma unroll
            for (int j = 0; j < 4; ++j) {
                acc[0] += ww[j] * bf2f((u16)(pp[j] & 0xffff));
                acc[1] += ww[j] * bf2f((u16)(pp[j] >> 16));
            }
        }
    }

    if constexpr (EPI != 4) {
#pragma unroll
        for (int v = 0; v < VEC; ++v) acc[v] += bias[lv + v];
    }

    if constexpr (EPI == 0) {
        *(float2*)(out + base) = make_float2(acc[0], acc[1]);
    } else if constexpr (EPI == 4) {
        *(u32*)(outb + base) = pack2(acc[0], acc[1]);
    } else if constexpr (EPI == 1) {
        float ss = 0.f;
#pragma unroll
        for (int v = 0; v < VEC; ++v) ss += acc[v] * acc[v];
#pragma unroll
        for (int off = 32; off; off >>= 1) ss += __shfl_xor(ss, off);
        float scale = 1.0f / fmaxf(sqrtf(ss), 1e-12f);
        uint2 p;
        p.x = pack2(acc[0] * scale, acc[1] * scale);
        p.y = pack2(acc[2] * scale, acc[3] * scale);
        *(uint2*)(outb + base) = p;
    } else {  // EPI == 3, VEC == 4
        uint2 zp = *(const uint2*)(Zb + base);
        float k0 = acc[0] + bf2f((u16)(zp.x & 0xffff));
        float k1 = acc[1] + bf2f((u16)(zp.x >> 16));
        float k2 = acc[2] + bf2f((u16)(zp.y & 0xffff));
        float k3 = acc[3] + bf2f((u16)(zp.y >> 16));
        uint2 ap = accInit ? *(const uint2*)(X0bb + base)
                           : *(const uint2*)(ACCb + base);
        float a0 = bf2f((u16)(ap.x & 0xffff)) + ca * k0;
        float a1 = bf2f((u16)(ap.x >> 16))    + ca * k1;
        float a2 = bf2f((u16)(ap.y & 0xffff)) + ca * k2;
        float a3 = bf2f((u16)(ap.y >> 16))    + ca * k3;
        uint2 av;
        av.x = pack2(a0, a1);
        av.y = pack2(a2, a3);
        *(uint2*)(ACCb + base) = av;
        if (writeXT) {
            uint2 xp = *(const uint2*)(X0bb + base);
            float x0 = bf2f((u16)(xp.x & 0xffff));
            float x1 = bf2f((u16)(xp.x >> 16));
            float x2 = bf2f((u16)(xp.y & 0xffff));
            float x3 = bf2f((u16)(xp.y >> 16));
            uint2 p;
            p.x = pack2(x0 + cx * k0, x1 + cx * k1);
            p.y = pack2(x2 + cx * k2, x3 + cx * k3);
            *(uint2*)(outb + base) = p;
        }
    }
}

// ---------------- launch ----------------

extern "C" void kernel_launch(void* const* d_in, const int* in_sizes, int n_in,
                              void* d_out, int out_size, void* d_ws, size_t ws_size,
                              hipStream_t stream) {
    const float* emb = (const float*)d_in[0];
    const int* ei    = (const int*)d_in[1];
    const float* W1  = (const float*)d_in[2];
    const float* b1  = (const float*)d_in[3];
    const float* Wf1 = (const float*)d_in[4];
    const float* bf1 = (const float*)d_in[5];
    const float* Wf2 = (const float*)d_in[6];
    const float* bf2 = (const float*)d_in[7];
    const float* W2  = (const float*)d_in[8];
    const float* b2  = (const float*)d_in[9];
    float* out = (float*)d_out;

    const int N = in_sizes[0] / NINP;  // 50000
    const int E = in_sizes[1] / 2;     // 800000
    const int* esrc = ei;
    const int* edst = ei + E;
    const int Ecap = E + 8 * N;        // padded CSR capacity

    char* p = (char*)d_ws;
    auto alloc = [&](size_t bytes) -> char* {
        char* r = p;
        p += (bytes + 255) & ~(size_t)255;
        return r;
    };
    int*   deg       = (int*)alloc((size_t)N * 4);
    float* dinv      = (float*)alloc((size_t)N * 4);
    int*   row_start = (int*)alloc((size_t)(N + 1) * 4);
    int*   cursor    = (int*)alloc((size_t)N * 4);
    int*   sc_excl   = (int*)alloc((size_t)N * 4);
    int*   sc_bsum   = (int*)alloc((size_t)1024 * 4);
    int*   csr_src   = (int*)alloc((size_t)Ecap * 4);
    float* csr_w     = (float*)alloc((size_t)Ecap * 4);
    u16*   Hb    = (u16*)alloc((size_t)N * D2 * 2);
    u8*    Hq    = (u8*)alloc((size_t)N * D2);       // fp8 gather table (EPI1 + EPI3 inputs)
    u16*   ACCb  = (u16*)alloc((size_t)N * D2 * 2);  // RK4 accumulator (bf16)
    u16*   X0b   = (u16*)alloc((size_t)N * D2 * 2);
    u16*   XTb   = (u16*)alloc((size_t)N * D2 * 2);  // aliased by embb (disjoint lifetime)
    u16*   Z1b   = (u16*)alloc((size_t)N * D2 * 2);
    u16*   Eb    = (u16*)alloc((size_t)N * NINP * 2); // S·emb (bf16)
    u16*   W1t   = (u16*)alloc((size_t)NINP * D2 * 2);
    u16*   Wf1t  = (u16*)alloc((size_t)D2 * D2 * 2);
    u16*   Wf2t  = (u16*)alloc((size_t)D2 * D2 * 2);
    u16*   W2t   = (u16*)alloc((size_t)D2 * NINP * 2);
    u16*   embb  = XTb;

    const int gN = (N + 255) / 256, gE = (E + 255) / 256;
    const int gE2 = (E + 511) / 512;
    init_deg_kernel<<<gN, 256, 0, stream>>>(deg, N);
    count_kernel<<<gE2, 256, 0, stream>>>(edst, deg, E);
    dinv_kernel<<<gN, 256, 0, stream>>>(deg, dinv, N);
    init_csr_kernel<<<(Ecap + 255) / 256, 256, 0, stream>>>(csr_src, csr_w, Ecap);
    scan_blk_kernel<<<gN, 256, 0, stream>>>(deg, sc_excl, sc_bsum, N);
    scan_top_kernel<<<1, 1024, 0, stream>>>(sc_bsum, gN);
    scan_add_kernel<<<gN, 256, 0, stream>>>(sc_excl, sc_bsum, deg, row_start, cursor, N);
    fill_csr_kernel<<<gE2, 256, 0, stream>>>(esrc, edst, dinv, cursor, csr_src, csr_w, E);

    wt_kernel<<<(NINP * D2 + 255) / 256, 256, 0, stream>>>(W1, W1t, NINP, D2);
    wt_kernel<<<(D2 * D2 + 255) / 256, 256, 0, stream>>>(Wf1, Wf1t, D2, D2);
    wt_kernel<<<(D2 * D2 + 255) / 256, 256, 0, stream>>>(Wf2, Wf2t, D2, D2);
    wt_kernel<<<(D2 * NINP + 255) / 256, 256, 0, stream>>>(W2, W2t, D2, NINP);
    cvt_kernel<<<(N * NINP / 4 + 255) / 256, 256, 0, stream>>>((const float4*)emb, (uint2*)embb,
                                                               N * NINP / 4);

    auto gemmB = [&](const u16* A, const u16* Bt, u16* C, int K, int Ncols) {
        int nbm = (N + 127) / 128, nbn = Ncols / 128;
        gemm_bf16<0><<<nbm * nbn, 256, 0, stream>>>(A, Bt, (void*)C, N, K, Ncols, nbn);
    };
    auto gemmQ = [&](const u16* A, const u16* Bt, u8* C, int K, int Ncols) {
        int nbm = (N + 127) / 128, nbn = Ncols / 128;
        gemm_bf16<1><<<nbm * nbn, 256, 0, stream>>>(A, Bt, (void*)C, N, K, Ncols, nbn);
    };
    const int gAgg = (N + 3) / 4;

    // conv1 swapped: Eb = S·emb (128-dim gather), gemm, then bias+l2norm -> X0b
    agg_kernel<2, 4, 0><<<gAgg, 256, 0, stream>>>(embb, nullptr, nullptr, nullptr, nullptr,
                                                  row_start, csr_src, csr_w, dinv, nullptr, Eb,
                                                  0.f, 0.f, 0, 0, N);
    gemmB(Eb, W1t, Hb, NINP, D2);
    l2n_kernel<<<gAgg, 256, 0, stream>>>(Hb, b1, X0b, N);

    // f(z) + fused RK4 stage: BOTH inner gathers on fp8 tables (Hq reused sequentially)
    auto fstage = [&](const u16* zb, const u16* zres, float ca, float cx, int accInit,
                      int writeXT, u16* outb) {
        gemmQ(zb, Wf1t, Hq, D2, D2);
        agg_kernel<4, 1, 1><<<gAgg, 256, 0, stream>>>(Hq, bf1, nullptr, nullptr, nullptr,
                                                      row_start, csr_src, csr_w, dinv, nullptr,
                                                      Z1b, 0.f, 0.f, 0, 0, N);
        gemmQ(Z1b, Wf2t, Hq, D2, D2);
        agg_kernel<4, 3, 1><<<gAgg, 256, 0, stream>>>(Hq, bf2, zres, X0b, ACCb,
                                                      row_start, csr_src, csr_w, dinv, nullptr,
                                                      outb, ca, cx, accInit, writeXT, N);
    };

    fstage(X0b, X0b, 1.f / 6.f, 0.5f, 1, 1, XTb);     // k1
    fstage(XTb, XTb, 1.f / 3.f, 0.5f, 0, 1, XTb);     // k2
    fstage(XTb, XTb, 1.f / 3.f, 1.0f, 0, 1, XTb);     // k3
    fstage(XTb, XTb, 1.f / 6.f, 0.0f, 0, 0, nullptr); // k4 -> ACCb (bf16)

    // final conv -> d_out (fp32)
    gemmB(ACCb, W2t, Hb, D2, NINP);
    agg_kernel<2, 0, 0><<<gAgg, 256, 0, stream>>>(Hb, b2, nullptr, nullptr, nullptr,
                                                  row_start, csr_src, csr_w, dinv, out, nullptr,
                                                  0.f, 0.f, 0, 0, N);
}